// Round 13
// baseline (60.386 us; speedup 1.0000x reference)
//
#include <hip/hip_runtime.h>

#define NV 320
#define GV 640
#define DHALF 128
#define BSROWS 2048
#define K_DIM 512
#define LDA 40      // f16 per LDS row (32 + 8 pad)
#define NMT 128     // number of 16-row tiles per group
#define NBLK 256

typedef _Float16 half8 __attribute__((ext_vector_type(8)));
typedef float floatx4 __attribute__((ext_vector_type(4)));

#define MFMA16(a, b, c) __builtin_amdgcn_mfma_f32_16x16x32_f16(a, b, c, 0, 0, 0)

// ---------------- Single fused kernel: GEMM + row phase + last-block perp tail -------------
__global__ __launch_bounds__(256) void gemm_row_kernel(
    const float* __restrict__ X, const float* __restrict__ W,
    const float* __restrict__ bias, const float* __restrict__ gum,
    const float* __restrict__ cvs, float* __restrict__ out,
    float* __restrict__ part, int* __restrict__ counter,
    float* __restrict__ perpOut) {
  __shared__ _Float16 Ah[2][16 * LDA], Al[2][16 * LDA];
  __shared__ float sm_m[4][16], sm_av[4][16], sm_s[4][16];
  __shared__ int sm_ai[4][16], sm_idx[16];
  __shared__ int lastFlag;

  const int tid = threadIdx.x;
  const int bid = blockIdx.x;
  const int g = bid & 1;
  const int mtile = bid >> 1;  // 0..127
  const int bm = mtile * 16;
  const int w = tid >> 6, lane = tid & 63;
  const int wcol0 = w * 80;
  const int gn0 = g * NV;

  // A staging: srow = tid>>4 (0..15), skc = (tid&15)*2 (float2 per thread)
  const int srow = tid >> 4, skc = (tid & 15) << 1;
  const float* Xg = X + (bm + srow) * K_DIM + skc;
  const int sA = srow * LDA + skc;

  const int frow = lane & 15;        // A row-in-tile / B col-in-16
  const int rq0 = (lane >> 4) << 2;  // C/D row base
  const int fkg = (lane >> 4) << 3;  // k offset of fragment
  const float* Wf = W + gn0 + wcol0 + frow;

  // ---- gumbel prefetch (hidden under the GEMM) ----
  float gv[5][4];
#pragma unroll
  for (int q = 0; q < 4; ++q) {
    const int r = bm + rq0 + q;
    const float* gr = gum + (2 * r + g) * NV + wcol0 + frow;
#pragma unroll
    for (int j = 0; j < 5; ++j) gv[j][q] = gr[j * 16];
  }

  floatx4 acc[5] = {};

  auto stageA = [&](int buf, float2 xv) {
#pragma unroll
    for (int j = 0; j < 2; ++j) {
      float s = ((j == 0) ? xv.x : xv.y) * 64.0f;
      _Float16 h = (_Float16)s;
      Ah[buf][sA + j] = h;
      Al[buf][sA + j] = (_Float16)(s - (float)h);
    }
  };
  auto loadW = [&](int k0, float (&wv)[5][8]) {
#pragma unroll
    for (int j = 0; j < 5; ++j)
#pragma unroll
      for (int kk = 0; kk < 8; ++kk)
        wv[j][kk] = Wf[(k0 + fkg + kk) * GV + j * 16];
  };
  auto computeTile = [&](int buf, const float (&wv)[5][8]) {
    half8 ah = *(const half8*)&Ah[buf][frow * LDA + fkg];
    half8 al = *(const half8*)&Al[buf][frow * LDA + fkg];
#pragma unroll
    for (int j = 0; j < 5; ++j) {
      half8 bh, bl;
#pragma unroll
      for (int kk = 0; kk < 8; ++kk) {
        float s = wv[j][kk] * 1024.0f;
        _Float16 h = (_Float16)s;
        bh[kk] = h;
        bl[kk] = (_Float16)(s - (float)h);
      }
      // per-output order hh, hl, lh (bit-identical to validated rounds)
      acc[j] = MFMA16(ah, bh, acc[j]);
      acc[j] = MFMA16(ah, bl, acc[j]);
      acc[j] = MFMA16(al, bh, acc[j]);
    }
  };

  float wvA[5][8], wvB[5][8];
  stageA(0, *(const float2*)(Xg));
  loadW(0, wvA);
  __syncthreads();

  // 8 iterations, 2 k-tiles each; A double-buffer 0/1; W reg double-buffer A/B
  for (int k0 = 0; k0 < K_DIM; k0 += 64) {
    const bool more = (k0 + 64) < K_DIM;

    float2 xv1 = *(const float2*)(Xg + k0 + 32);
    loadW(k0 + 32, wvB);            // prefetch odd tile
    computeTile(0, wvA);            // compute even tile
    stageA(1, xv1);
    __syncthreads();

    float2 xv2;
    if (more) {
      xv2 = *(const float2*)(Xg + k0 + 64);
      loadW(k0 + 64, wvA);          // prefetch next even tile
    }
    computeTile(1, wvB);            // compute odd tile
    if (more) stageA(0, xv2);
    __syncthreads();
  }

  // ---------------- epilogue ----------------
  const float inv = 1.0f / 65536.0f;
#pragma unroll
  for (int j = 0; j < 5; ++j) {
    const float bb = bias[gn0 + wcol0 + j * 16 + frow];
#pragma unroll
    for (int q = 0; q < 4; ++q) acc[j][q] = acc[j][q] * inv + bb;
  }

  // per-row max (raw logits) + argmax (l+gumbel, tie -> lowest col), 16-lane tree
  float m[4], bv[4];
  int bi[4];
#pragma unroll
  for (int q = 0; q < 4; ++q) {
    float mm = acc[0][q];
    float av = acc[0][q] + gv[0][q];
    int ai = wcol0 + frow;
#pragma unroll
    for (int j = 1; j < 5; ++j) {
      mm = fmaxf(mm, acc[j][q]);
      float a2 = acc[j][q] + gv[j][q];
      if (a2 > av) { av = a2; ai = wcol0 + j * 16 + frow; }
    }
#pragma unroll
    for (int o = 1; o < 16; o <<= 1) {
      mm = fmaxf(mm, __shfl_xor(mm, o));
      float ov = __shfl_xor(av, o);
      int oi = __shfl_xor(ai, o);
      if (ov > av || (ov == av && oi < ai)) { av = ov; ai = oi; }
    }
    m[q] = mm; bv[q] = av; bi[q] = ai;
  }
  if (frow == 0) {
#pragma unroll
    for (int q = 0; q < 4; ++q) {
      sm_m[w][rq0 + q] = m[q];
      sm_av[w][rq0 + q] = bv[q];
      sm_ai[w][rq0 + q] = bi[q];
    }
  }
  __syncthreads();

  float gm[4];
#pragma unroll
  for (int q = 0; q < 4; ++q) {
    const int row = rq0 + q;
    float mm = sm_m[0][row];
    float av = sm_av[0][row];
    int ai = sm_ai[0][row];
#pragma unroll
    for (int ww = 1; ww < 4; ++ww) {
      mm = fmaxf(mm, sm_m[ww][row]);
      float v2 = sm_av[ww][row];
      int i2 = sm_ai[ww][row];
      if (v2 > av || (v2 == av && i2 < ai)) { av = v2; ai = i2; }
    }
    gm[q] = mm;
    if (w == 0 && frow == 0) sm_idx[row] = ai;
  }

  // exp + per-row sum
  float rs[4];
#pragma unroll
  for (int q = 0; q < 4; ++q) {
    float s = 0.f;
#pragma unroll
    for (int j = 0; j < 5; ++j) {
      float e = expf(acc[j][q] - gm[q]);
      acc[j][q] = e;
      s += e;
    }
#pragma unroll
    for (int o = 1; o < 16; o <<= 1) s += __shfl_xor(s, o);
    rs[q] = s;
  }
  if (frow == 0)
#pragma unroll
    for (int q = 0; q < 4; ++q) sm_s[w][rq0 + q] = rs[q];
  __syncthreads();

  float rinv[4];
#pragma unroll
  for (int q = 0; q < 4; ++q) {
    const int row = rq0 + q;
    rinv[q] = 1.f / ((sm_s[0][row] + sm_s[1][row]) + (sm_s[2][row] + sm_s[3][row]));
  }

  // marginal partials: col-sum over this block's 16 rows
#pragma unroll
  for (int j = 0; j < 5; ++j) {
    float p = 0.f;
#pragma unroll
    for (int q = 0; q < 4; ++q) p += acc[j][q] * rinv[q];
    p += __shfl_xor(p, 16);
    p += __shfl_xor(p, 32);
    if (lane < 16) part[(g * NMT + mtile) * NV + wcol0 + j * 16 + lane] = p;
  }

  // fused gather: 16 rows x 128 floats = 512 float4, 2 iters of 256 threads
#pragma unroll
  for (int it = 0; it < 2; ++it) {
    const int f4 = tid + it * 256;
    const int row = f4 >> 5;
    const int d = (f4 & 31) << 2;
    const int id = sm_idx[row];
    const float4 v = *(const float4*)(cvs + (g * NV + id) * DHALF + d);
    *(float4*)(out + (bm + row) * 256 + g * DHALF + d) = v;
  }

  // ---------------- last-block-done perp tail ----------------
  // No counter zeroing: exactly NBLK increments/launch -> (old & (NBLK-1)) == NBLK-1
  // identifies the last block for ANY starting counter value (wrap-safe).
  __threadfence();
  __syncthreads();
  if (tid == 0) {
    const int old = atomicAdd(counter, 1);
    lastFlag = ((old & (NBLK - 1)) == (NBLK - 1)) ? 1 : 0;
  }
  __syncthreads();

  if (lastFlag) {
    __threadfence();
    float h0 = 0.f, h1 = 0.f;
    // cols assigned to threads; inner loop over b is a coalesced 256-wide sweep
#pragma unroll
    for (int c0 = 0; c0 < GV; c0 += 256) {
      const int col = c0 + tid;
      if (col < GV) {
        const int gg = (col >= NV) ? 1 : 0;
        const int c = col - gg * NV;
        float s = 0.f;
        for (int b = 0; b < NMT; ++b) s += part[(gg * NMT + b) * NV + c];
        const float mm = s * (1.0f / BSROWS);
        const float t = mm * logf(mm + 1e-7f);
        if (gg == 0) h0 += t; else h1 += t;
      }
    }
    __shared__ float r0[256], r1[256];
    r0[tid] = h0;
    r1[tid] = h1;
    __syncthreads();
    for (int s = 128; s > 0; s >>= 1) {
      if (tid < s) { r0[tid] += r0[tid + s]; r1[tid] += r1[tid + s]; }
      __syncthreads();
    }
    if (tid == 0) perpOut[0] = expf(-r0[0]) + expf(-r1[0]);
  }
}

extern "C" void kernel_launch(void* const* d_in, const int* in_sizes, int n_in,
                              void* d_out, int out_size, void* d_ws, size_t ws_size,
                              hipStream_t stream) {
  const float* x = (const float*)d_in[0];
  const float* W = (const float*)d_in[1];
  const float* b = (const float*)d_in[2];
  const float* cvs = (const float*)d_in[3];
  const float* gum = (const float*)d_in[4];
  float* out = (float*)d_out;

  float* part = (float*)d_ws;                 // 256*320 f32
  int* counter = (int*)(part + 2 * NMT * NV); // 1 i32 (never reset; residue trick)

  gemm_row_kernel<<<NBLK, 256, 0, stream>>>(x, W, b, gum, cvs, out, part, counter,
                                            out + BSROWS * 256);
}

// Round 14
// 41.486 us; speedup vs baseline: 1.4556x; 1.4556x over previous
//
#include <hip/hip_runtime.h>

#define NV 320
#define GV 640
#define DHALF 128
#define BSROWS 2048
#define K_DIM 512
#define LDA 40      // f16 per LDS row (32 + 8 pad)
#define NRED 40
#define NMT 256     // number of 8-row tiles per group

typedef _Float16 half8 __attribute__((ext_vector_type(8)));
typedef float floatx4 __attribute__((ext_vector_type(4)));

#define MFMA16(a, b, c) __builtin_amdgcn_mfma_f32_16x16x32_f16(a, b, c, 0, 0, 0)

// ---------------- Fused GEMM + row phase: 512 blocks, 8 rows x one group each --------------
// BM=8: MFMA rows 8..15 are duplicates of 0..7 (srow&7 staging, frow&7 fragment read).
// Dup lanes (rq0>=8) mirror rows via rq0&7 and contribute 0 to partials.
__global__ __launch_bounds__(256) void gemm_row_kernel(
    const float* __restrict__ X, const float* __restrict__ W,
    const float* __restrict__ bias, const float* __restrict__ gum,
    const float* __restrict__ cvs, float* __restrict__ out,
    float* __restrict__ part, int* __restrict__ counter) {
  __shared__ _Float16 Ah[2][8 * LDA], Al[2][8 * LDA];
  __shared__ float sm_m[4][16], sm_av[4][16], sm_s[4][16];
  __shared__ int sm_ai[4][16], sm_idx[16];

  const int tid = threadIdx.x;
  const int bid = blockIdx.x;
  if (bid == 0 && tid == 0) *counter = 0;
  const int g = bid & 1;
  const int mtile = bid >> 1;  // 0..255
  const int bm = mtile * 8;
  const int w = tid >> 6, lane = tid & 63;
  const int wcol0 = w * 80;
  const int gn0 = g * NV;

  // A staging: 8 rows x 32 k = 256 f32; one f32 (hi+lo) per thread
  const int srow = tid >> 5, skc = tid & 31;
  const float* Xg = X + (bm + srow) * K_DIM + skc;
  const int sA = srow * LDA + skc;

  const int frow = lane & 15;        // B col-in-16; A row via frow&7
  const int arow = frow & 7;
  const int rq0 = (lane >> 4) << 2;  // C/D row base (0,4,8,12)
  const int rq = rq0 & 7;            // mirrored valid row base (0,4)
  const bool dup = rq0 >= 8;
  const int fkg = (lane >> 4) << 3;  // k offset of fragment
  const float* Wf = W + gn0 + wcol0 + frow;

  // ---- gumbel prefetch (mirrored rows for dup lanes; no OOB) ----
  float gv[5][4];
#pragma unroll
  for (int q = 0; q < 4; ++q) {
    const int r = bm + rq + q;
    const float* gr = gum + (2 * r + g) * NV + wcol0 + frow;
#pragma unroll
    for (int j = 0; j < 5; ++j) gv[j][q] = gr[j * 16];
  }

  floatx4 acc[5] = {};

  auto stageA = [&](int buf, float xv) {
    float s = xv * 64.0f;
    _Float16 h = (_Float16)s;
    Ah[buf][sA] = h;
    Al[buf][sA] = (_Float16)(s - (float)h);
  };
  auto loadW = [&](int k0, float (&wv)[5][8]) {
#pragma unroll
    for (int j = 0; j < 5; ++j)
#pragma unroll
      for (int kk = 0; kk < 8; ++kk)
        wv[j][kk] = Wf[(k0 + fkg + kk) * GV + j * 16];
  };
  auto computeTile = [&](int buf, const float (&wv)[5][8]) {
    half8 ah = *(const half8*)&Ah[buf][arow * LDA + fkg];
    half8 al = *(const half8*)&Al[buf][arow * LDA + fkg];
#pragma unroll
    for (int j = 0; j < 5; ++j) {
      half8 bh, bl;
#pragma unroll
      for (int kk = 0; kk < 8; ++kk) {
        float s = wv[j][kk] * 1024.0f;
        _Float16 h = (_Float16)s;
        bh[kk] = h;
        bl[kk] = (_Float16)(s - (float)h);
      }
      // per-output order hh, hl, lh (bit-identical to validated rounds)
      acc[j] = MFMA16(ah, bh, acc[j]);
      acc[j] = MFMA16(ah, bl, acc[j]);
      acc[j] = MFMA16(al, bh, acc[j]);
    }
  };

  float wvA[5][8], wvB[5][8];
  stageA(0, *Xg);
  loadW(0, wvA);
  __syncthreads();

  // 8 iterations, 2 k-tiles each; A double-buffer 0/1; W reg double-buffer A/B
  for (int k0 = 0; k0 < K_DIM; k0 += 64) {
    const bool more = (k0 + 64) < K_DIM;

    float xv1 = Xg[k0 + 32];
    loadW(k0 + 32, wvB);            // prefetch odd tile
    computeTile(0, wvA);            // compute even tile
    stageA(1, xv1);
    __syncthreads();

    float xv2 = 0.f;
    if (more) {
      xv2 = Xg[k0 + 64];
      loadW(k0 + 64, wvA);          // prefetch next even tile
    }
    computeTile(1, wvB);            // compute odd tile
    if (more) stageA(0, xv2);
    __syncthreads();
  }

  // ---------------- epilogue ----------------
  const float inv = 1.0f / 65536.0f;
#pragma unroll
  for (int j = 0; j < 5; ++j) {
    const float bb = bias[gn0 + wcol0 + j * 16 + frow];
#pragma unroll
    for (int q = 0; q < 4; ++q) acc[j][q] = acc[j][q] * inv + bb;
  }

  // per-row max (raw logits) + argmax (l+gumbel, tie -> lowest col), 16-lane tree
  float m[4], bv[4];
  int bi[4];
#pragma unroll
  for (int q = 0; q < 4; ++q) {
    float mm = acc[0][q];
    float av = acc[0][q] + gv[0][q];
    int ai = wcol0 + frow;
#pragma unroll
    for (int j = 1; j < 5; ++j) {
      mm = fmaxf(mm, acc[j][q]);
      float a2 = acc[j][q] + gv[j][q];
      if (a2 > av) { av = a2; ai = wcol0 + j * 16 + frow; }
    }
#pragma unroll
    for (int o = 1; o < 16; o <<= 1) {
      mm = fmaxf(mm, __shfl_xor(mm, o));
      float ov = __shfl_xor(av, o);
      int oi = __shfl_xor(ai, o);
      if (ov > av || (ov == av && oi < ai)) { av = ov; ai = oi; }
    }
    m[q] = mm; bv[q] = av; bi[q] = ai;
  }
  if (frow == 0) {
#pragma unroll
    for (int q = 0; q < 4; ++q) {
      sm_m[w][rq0 + q] = m[q];
      sm_av[w][rq0 + q] = bv[q];
      sm_ai[w][rq0 + q] = bi[q];
    }
  }
  __syncthreads();

  float gm[4];
#pragma unroll
  for (int q = 0; q < 4; ++q) {
    const int row = rq0 + q;
    float mm = sm_m[0][row];
    float av = sm_av[0][row];
    int ai = sm_ai[0][row];
#pragma unroll
    for (int ww = 1; ww < 4; ++ww) {
      mm = fmaxf(mm, sm_m[ww][row]);
      float v2 = sm_av[ww][row];
      int i2 = sm_ai[ww][row];
      if (v2 > av || (v2 == av && i2 < ai)) { av = v2; ai = i2; }
    }
    gm[q] = mm;
    if (w == 0 && frow == 0) sm_idx[row] = ai;
  }

  // exp + per-row sum
  float rs[4];
#pragma unroll
  for (int q = 0; q < 4; ++q) {
    float s = 0.f;
#pragma unroll
    for (int j = 0; j < 5; ++j) {
      float e = expf(acc[j][q] - gm[q]);
      acc[j][q] = e;
      s += e;
    }
#pragma unroll
    for (int o = 1; o < 16; o <<= 1) s += __shfl_xor(s, o);
    rs[q] = s;
  }
  if (frow == 0)
#pragma unroll
    for (int q = 0; q < 4; ++q) sm_s[w][rq0 + q] = rs[q];
  __syncthreads();

  float rinv[4];
#pragma unroll
  for (int q = 0; q < 4; ++q) {
    const int row = rq0 + q;
    rinv[q] = 1.f / ((sm_s[0][row] + sm_s[1][row]) + (sm_s[2][row] + sm_s[3][row]));
  }

  // marginal partials: col-sum over this block's 8 rows (dup lanes contribute 0)
#pragma unroll
  for (int j = 0; j < 5; ++j) {
    float p = 0.f;
#pragma unroll
    for (int q = 0; q < 4; ++q) p += dup ? 0.f : acc[j][q] * rinv[q];
    p += __shfl_xor(p, 16);
    p += __shfl_xor(p, 32);
    if (lane < 16) part[(g * NMT + mtile) * NV + wcol0 + j * 16 + lane] = p;
  }

  // fused gather: 8 rows x 128 floats = 256 float4, one per thread
  {
    const int row = tid >> 5;
    const int d = (tid & 31) << 2;
    const int id = sm_idx[row];
    const float4 v = *(const float4*)(cvs + (g * NV + id) * DHALF + d);
    *(float4*)(out + (bm + row) * 256 + g * DHALF + d) = v;
  }
}

// ---------------- Reduce partials + perplexity: 40 blocks x 16 cols, 256 partials/group ----
__global__ __launch_bounds__(256) void reduce_perp_kernel(
    const float* __restrict__ part, float* __restrict__ hpart,
    int* __restrict__ counter, float* __restrict__ perpOut) {
  const int t = threadIdx.x;
  const int rg = t >> 4, co = t & 15;
  const int col = blockIdx.x * 16 + co;  // 0..639; blocks 0..19 group0, 20..39 group1
  const int g = (col >= NV) ? 1 : 0;
  const int c = col - g * NV;
  float s = 0.f;
  for (int b = rg; b < NMT; b += 16) s += part[(g * NMT + b) * NV + c];
  __shared__ float red[16][16];
  red[rg][co] = s;
  __syncthreads();
  if (t < 16) {
    float cs = 0.f;
#pragma unroll
    for (int j = 0; j < 16; ++j) cs += red[j][t];
    const float mm = cs * (1.0f / BSROWS);
    float h = mm * logf(mm + 1e-7f);
#pragma unroll
    for (int o = 8; o > 0; o >>= 1) h += __shfl_xor(h, o, 16);
    if (t == 0) {
      hpart[blockIdx.x] = h;
      __threadfence();
      const int old = atomicAdd(counter, 1);
      if (old == NRED - 1) {
        __threadfence();
        float h0 = 0.f, h1 = 0.f;
#pragma unroll
        for (int i = 0; i < 20; ++i) h0 += hpart[i];
#pragma unroll
        for (int i = 20; i < 40; ++i) h1 += hpart[i];
        perpOut[0] = expf(-h0) + expf(-h1);
      }
    }
  }
}

extern "C" void kernel_launch(void* const* d_in, const int* in_sizes, int n_in,
                              void* d_out, int out_size, void* d_ws, size_t ws_size,
                              hipStream_t stream) {
  const float* x = (const float*)d_in[0];
  const float* W = (const float*)d_in[1];
  const float* b = (const float*)d_in[2];
  const float* cvs = (const float*)d_in[3];
  const float* gum = (const float*)d_in[4];
  float* out = (float*)d_out;

  float* part = (float*)d_ws;                 // 512*320 f32
  float* hpart = part + 2 * NMT * NV;         // 40 f32 (+pad)
  int* counter = (int*)(hpart + 64);          // 1 i32

  gemm_row_kernel<<<2 * NMT, 256, 0, stream>>>(x, W, b, gum, cvs, out, part, counter);
  reduce_perp_kernel<<<NRED, 256, 0, stream>>>(part, hpart, counter, out + BSROWS * 256);
}

// Round 15
// 27.949 us; speedup vs baseline: 2.1606x; 1.4844x over previous
//
#include <hip/hip_runtime.h>

#define NV 320
#define GV 640
#define DHALF 128
#define BSROWS 2048
#define K_DIM 512
#define NRED 40
#define NMT 128     // number of 16-row tiles per group

typedef _Float16 half8 __attribute__((ext_vector_type(8)));
typedef float floatx4 __attribute__((ext_vector_type(4)));

#define MFMA16(a, b, c) __builtin_amdgcn_mfma_f32_16x16x32_f16(a, b, c, 0, 0, 0)

// ---------------- Fused GEMM + row phase: 256 blocks, 16 rows x one group, barrier-free ----
// A: per-lane direct global->reg fragment (row frow, k fkg..fkg+7), split x64 in-reg.
// B: W f32 prefetched to regs, split x1024 in-reg. No LDS / no syncthreads in k-loop.
__global__ __launch_bounds__(256) void gemm_row_kernel(
    const float* __restrict__ X, const float* __restrict__ W,
    const float* __restrict__ bias, const float* __restrict__ gum,
    const float* __restrict__ cvs, float* __restrict__ out,
    float* __restrict__ part, int* __restrict__ counter) {
  __shared__ float sm_m[4][16], sm_av[4][16], sm_s[4][16];
  __shared__ int sm_ai[4][16], sm_idx[16];

  const int tid = threadIdx.x;
  const int bid = blockIdx.x;
  if (bid == 0 && tid == 0) *counter = 0;
  const int g = bid & 1;
  const int mtile = bid >> 1;  // 0..127
  const int bm = mtile * 16;
  const int w = tid >> 6, lane = tid & 63;
  const int wcol0 = w * 80;
  const int gn0 = g * NV;

  const int frow = lane & 15;        // A row-in-tile / B col-in-16
  const int rq0 = (lane >> 4) << 2;  // C/D row base
  const int fkg = (lane >> 4) << 3;  // k offset of fragment
  const float* Xa = X + (bm + frow) * K_DIM + fkg;
  const float* Wf = W + gn0 + wcol0 + frow;

  // ---- prefetch gumbels + bias (hidden under the GEMM) ----
  float gv[5][4];
#pragma unroll
  for (int q = 0; q < 4; ++q) {
    const int r = bm + rq0 + q;
    const float* gr = gum + (2 * r + g) * NV + wcol0 + frow;
#pragma unroll
    for (int j = 0; j < 5; ++j) gv[j][q] = gr[j * 16];
  }
  float bb[5];
#pragma unroll
  for (int j = 0; j < 5; ++j) bb[j] = bias[gn0 + wcol0 + j * 16 + frow];

  floatx4 acc[5] = {};

  auto loadW = [&](int k0, float (&wv)[5][8]) {
#pragma unroll
    for (int j = 0; j < 5; ++j)
#pragma unroll
      for (int kk = 0; kk < 8; ++kk)
        wv[j][kk] = Wf[(k0 + fkg + kk) * GV + j * 16];
  };
  auto computeTile = [&](float4 xa, float4 xb, const float (&wv)[5][8]) {
    // A split x64 (identical formula/order to validated LDS path)
    float xv[8] = {xa.x, xa.y, xa.z, xa.w, xb.x, xb.y, xb.z, xb.w};
    half8 ah, al;
#pragma unroll
    for (int j = 0; j < 8; ++j) {
      float s = xv[j] * 64.0f;
      _Float16 h = (_Float16)s;
      ah[j] = h;
      al[j] = (_Float16)(s - (float)h);
    }
#pragma unroll
    for (int j = 0; j < 5; ++j) {
      half8 bh, bl;
#pragma unroll
      for (int kk = 0; kk < 8; ++kk) {
        float s = wv[j][kk] * 1024.0f;
        _Float16 h = (_Float16)s;
        bh[kk] = h;
        bl[kk] = (_Float16)(s - (float)h);
      }
      // per-output order hh, hl, lh (bit-identical to validated rounds)
      acc[j] = MFMA16(ah, bh, acc[j]);
      acc[j] = MFMA16(ah, bl, acc[j]);
      acc[j] = MFMA16(al, bh, acc[j]);
    }
  };

  float wvA[5][8], wvB[5][8];
  float4 xaA, xbA, xaB, xbB;
  xaA = *(const float4*)(Xa);
  xbA = *(const float4*)(Xa + 4);
  loadW(0, wvA);

  // 8 iterations, 2 k-tiles each; A and W reg-double-buffered; NO barriers
  for (int k0 = 0; k0 < K_DIM; k0 += 64) {
    const bool more = (k0 + 64) < K_DIM;

    xaB = *(const float4*)(Xa + k0 + 32);
    xbB = *(const float4*)(Xa + k0 + 36);
    loadW(k0 + 32, wvB);            // prefetch odd tile
    computeTile(xaA, xbA, wvA);     // compute even tile

    if (more) {
      xaA = *(const float4*)(Xa + k0 + 64);
      xbA = *(const float4*)(Xa + k0 + 68);
      loadW(k0 + 64, wvA);          // prefetch next even tile
    }
    computeTile(xaB, xbB, wvB);     // compute odd tile
  }

  // ---------------- epilogue (R12-validated) ----------------
  const float inv = 1.0f / 65536.0f;
#pragma unroll
  for (int j = 0; j < 5; ++j)
#pragma unroll
    for (int q = 0; q < 4; ++q) acc[j][q] = acc[j][q] * inv + bb[j];

  // per-row max (raw logits) + argmax (l+gumbel, tie -> lowest col), 16-lane tree
  float m[4], bv[4];
  int bi[4];
#pragma unroll
  for (int q = 0; q < 4; ++q) {
    float mm = acc[0][q];
    float av = acc[0][q] + gv[0][q];
    int ai = wcol0 + frow;
#pragma unroll
    for (int j = 1; j < 5; ++j) {
      mm = fmaxf(mm, acc[j][q]);
      float a2 = acc[j][q] + gv[j][q];
      if (a2 > av) { av = a2; ai = wcol0 + j * 16 + frow; }
    }
#pragma unroll
    for (int o = 1; o < 16; o <<= 1) {
      mm = fmaxf(mm, __shfl_xor(mm, o));
      float ov = __shfl_xor(av, o);
      int oi = __shfl_xor(ai, o);
      if (ov > av || (ov == av && oi < ai)) { av = ov; ai = oi; }
    }
    m[q] = mm; bv[q] = av; bi[q] = ai;
  }
  if (frow == 0) {
#pragma unroll
    for (int q = 0; q < 4; ++q) {
      sm_m[w][rq0 + q] = m[q];
      sm_av[w][rq0 + q] = bv[q];
      sm_ai[w][rq0 + q] = bi[q];
    }
  }
  __syncthreads();

  float gm[4];
#pragma unroll
  for (int q = 0; q < 4; ++q) {
    const int row = rq0 + q;
    float mm = sm_m[0][row];
    float av = sm_av[0][row];
    int ai = sm_ai[0][row];
#pragma unroll
    for (int ww = 1; ww < 4; ++ww) {
      mm = fmaxf(mm, sm_m[ww][row]);
      float v2 = sm_av[ww][row];
      int i2 = sm_ai[ww][row];
      if (v2 > av || (v2 == av && i2 < ai)) { av = v2; ai = i2; }
    }
    gm[q] = mm;
    if (w == 0 && frow == 0) sm_idx[row] = ai;
  }

  // exp + per-row sum
  float rs[4];
#pragma unroll
  for (int q = 0; q < 4; ++q) {
    float s = 0.f;
#pragma unroll
    for (int j = 0; j < 5; ++j) {
      float e = expf(acc[j][q] - gm[q]);
      acc[j][q] = e;
      s += e;
    }
#pragma unroll
    for (int o = 1; o < 16; o <<= 1) s += __shfl_xor(s, o);
    rs[q] = s;
  }
  if (frow == 0)
#pragma unroll
    for (int q = 0; q < 4; ++q) sm_s[w][rq0 + q] = rs[q];
  __syncthreads();

  float rinv[4];
#pragma unroll
  for (int q = 0; q < 4; ++q) {
    const int row = rq0 + q;
    rinv[q] = 1.f / ((sm_s[0][row] + sm_s[1][row]) + (sm_s[2][row] + sm_s[3][row]));
  }

  // marginal partials: col-sum over this block's 16 rows
#pragma unroll
  for (int j = 0; j < 5; ++j) {
    float p = 0.f;
#pragma unroll
    for (int q = 0; q < 4; ++q) p += acc[j][q] * rinv[q];
    p += __shfl_xor(p, 16);
    p += __shfl_xor(p, 32);
    if (lane < 16) part[(g * NMT + mtile) * NV + wcol0 + j * 16 + lane] = p;
  }

  // fused gather: 16 rows x 128 floats = 512 float4, 2 iters of 256 threads
#pragma unroll
  for (int it = 0; it < 2; ++it) {
    const int f4 = tid + it * 256;
    const int row = f4 >> 5;
    const int d = (f4 & 31) << 2;
    const int id = sm_idx[row];
    const float4 v = *(const float4*)(cvs + (g * NV + id) * DHALF + d);
    *(float4*)(out + (bm + row) * 256 + g * DHALF + d) = v;
  }
}

// ---------------- Reduce partials + perplexity: 40 blocks x 16 cols, 128 partials/group ----
__global__ __launch_bounds__(256) void reduce_perp_kernel(
    const float* __restrict__ part, float* __restrict__ hpart,
    int* __restrict__ counter, float* __restrict__ perpOut) {
  const int t = threadIdx.x;
  const int rg = t >> 4, co = t & 15;
  const int col = blockIdx.x * 16 + co;  // 0..639; blocks 0..19 group0, 20..39 group1
  const int g = (col >= NV) ? 1 : 0;
  const int c = col - g * NV;
  float s = 0.f;
  for (int b = rg; b < NMT; b += 16) s += part[(g * NMT + b) * NV + c];
  __shared__ float red[16][16];
  red[rg][co] = s;
  __syncthreads();
  if (t < 16) {
    float cs = 0.f;
#pragma unroll
    for (int j = 0; j < 16; ++j) cs += red[j][t];
    const float mm = cs * (1.0f / BSROWS);
    float h = mm * logf(mm + 1e-7f);
#pragma unroll
    for (int o = 8; o > 0; o >>= 1) h += __shfl_xor(h, o, 16);
    if (t == 0) {
      hpart[blockIdx.x] = h;
      __threadfence();
      const int old = atomicAdd(counter, 1);
      if (old == NRED - 1) {
        __threadfence();
        float h0 = 0.f, h1 = 0.f;
#pragma unroll
        for (int i = 0; i < 20; ++i) h0 += hpart[i];
#pragma unroll
        for (int i = 20; i < 40; ++i) h1 += hpart[i];
        perpOut[0] = expf(-h0) + expf(-h1);
      }
    }
  }
}

extern "C" void kernel_launch(void* const* d_in, const int* in_sizes, int n_in,
                              void* d_out, int out_size, void* d_ws, size_t ws_size,
                              hipStream_t stream) {
  const float* x = (const float*)d_in[0];
  const float* W = (const float*)d_in[1];
  const float* b = (const float*)d_in[2];
  const float* cvs = (const float*)d_in[3];
  const float* gum = (const float*)d_in[4];
  float* out = (float*)d_out;

  float* part = (float*)d_ws;                 // 256*320 f32
  float* hpart = part + 2 * NMT * NV;         // 40 f32 (+pad)
  int* counter = (int*)(hpart + 64);          // 1 i32

  gemm_row_kernel<<<256, 256, 0, stream>>>(x, W, b, gum, cvs, out, part, counter);
  reduce_perp_kernel<<<NRED, 256, 0, stream>>>(part, hpart, counter, out + BSROWS * 256);
}